// Round 5
// baseline (139.467 us; speedup 1.0000x reference)
//
#include <hip/hip_runtime.h>

// LocallyConnected2d: B=16, C=4, H=W=128, K=7, PAD=3, fp32.
// out[b,o,h,w] = mask * sum_{i,t} xpad[b,i,h+dy,w+dx] * wn[o,i,h,w,t]
// cw = weight + 1 at center tap (t=24) for ALL (o,i); wn = |cw|/sum_t|cw|.
//
// R5: same 3-dispatch streaming structure as R4; fused kernel rebuilt around
// the LDS-issue bottleneck (R4 model: 803K ds_read_b128 wave-instr ~ 15.7us
// was the critical path, FMA only 2.6us). Thread tile is now 2o x 4b so each
// x float4 LDS read feeds 8 FMAs -> LDS instr halved (401K ~ 7.8us), and
// weight L3 re-reads drop 4x -> 2x. Block = (bq,h) covers a full 128-w row:
// weight loads are 256B/wave coalesced; ONE barrier; no atomics.

#define HW   128
#define PW   134
#define NB   16
#define NC   4
#define KK   49
#define HWHW 16384

#define XTP_FLOATS (NC * PW * PW * NB)        // 1,149,184  (4.6 MB)
#define WT_FLOATS  (NC * NC * KK * HWHW)      // 12,845,056 (51.4 MB)

// ---------------- prep1: padded transpose x[b][i][h][w] -> xTp[i][hp][wp][b]
__global__ __launch_bounds__(256) void lc2d_prep(const float* __restrict__ x,
                                                 float* __restrict__ xTp) {
  int idx = blockIdx.x * 256 + threadIdx.x;          // (i, hp, wp)
  if (idx >= NC * PW * PW) return;
  int wp = idx % PW;
  int r  = idx / PW;
  int hp = r % PW;
  int i  = r / PW;
  int h = hp - 3, w = wp - 3;
  bool in = (h >= 0) & (h < HW) & (w >= 0) & (w < HW);
  float v[NB];
#pragma unroll
  for (int b = 0; b < NB; ++b)
    v[b] = in ? x[((b * NC + i) * HW + h) * HW + w] : 0.0f;
  float4* dst = (float4*)(xTp + (size_t)idx * NB);
  dst[0] = make_float4(v[0],  v[1],  v[2],  v[3]);
  dst[1] = make_float4(v[4],  v[5],  v[6],  v[7]);
  dst[2] = make_float4(v[8],  v[9],  v[10], v[11]);
  dst[3] = make_float4(v[12], v[13], v[14], v[15]);
}

// ---------------- prep2: normalize + transpose weights
// block = (o,i, h, whalf): 64 w x 49 t tile. grid 4096 x 256.
__global__ __launch_bounds__(256) void lc2d_wnorm(const float* __restrict__ weight,
                                                  float* __restrict__ wsT) {
  __shared__ __align__(16) float tile[64 * KK];      // [w][t], 12.25 KB
  const int tid   = threadIdx.x;
  const int bid   = blockIdx.x;
  const int whalf = bid & 1;
  const int h     = (bid >> 1) & 127;
  const int oi    = bid >> 8;                        // o*4+i, 0..15
  const int w0    = whalf * 64;
  const size_t base = ((size_t)oi * HWHW + h * HW + w0) * KK;
#pragma unroll
  for (int k = 0; k < 4; ++k) {
    int f = tid + k * 256;
    if (f < 784) *(float4*)&tile[4 * f] = *(const float4*)(weight + base + 4 * f);
  }
  __syncthreads();
  {
    const int r = tid >> 2, q = tid & 3;
    const int t0 = q * 12;                           // q==2 starts at t=24
    float v[13];
#pragma unroll
    for (int j = 0; j < 12; ++j) v[j] = tile[r * KK + t0 + j];
    v[12] = (q == 3) ? tile[r * KK + 48] : 0.f;
    float s = 0.f;
#pragma unroll
    for (int j = 0; j < 13; ++j) s += fabsf(v[j]);
    if (q == 2) s += fabsf(v[0] + 1.f) - fabsf(v[0]);  // center delta, ALL (o,i)
    s += __shfl_xor(s, 1);
    s += __shfl_xor(s, 2);
    const float inv = 1.f / s;
    if (q == 2) v[0] += 1.f;
#pragma unroll
    for (int j = 0; j < 12; ++j) tile[r * KK + t0 + j] = fabsf(v[j]) * inv;
    if (q == 3) tile[r * KK + 48] = fabsf(v[12]) * inv;
  }
  __syncthreads();
#pragma unroll
  for (int k = 0; k < 13; ++k) {
    int f = tid + k * 256;
    if (f < 3136) {
      int t = f >> 6, wl = f & 63;
      wsT[((size_t)oi * KK + t) * HWHW + h * HW + w0 + wl] = tile[wl * KK + t];
    }
  }
}

// ---------------- main: fused conv. block=(bq, h); thread=(oh, wt 0..127)
// Per thread: acc[2 o][4 b]; each x float4 LDS read feeds 8 FMAs.
__global__ __launch_bounds__(256) void lc2d_fused2(const float* __restrict__ wsT,
                                                   const float* __restrict__ xTp,
                                                   float* __restrict__ out) {
  __shared__ __align__(16) float4 tile4[NC * 7 * PW];   // [i][dy][wp], 60 KB
  const int tid = threadIdx.x;
  const int bid = blockIdx.x;
  const int h   = bid & 127;
  const int bq  = bid >> 7;                          // 0..3 (b-quad)
  const float4* __restrict__ xTp4 = (const float4*)xTp;

  // stage x rows h..h+6 (padded coords), all 4 i, this bq: 3752 float4s
  for (int f = tid; f < NC * 7 * PW; f += 256) {
    int i  = f / (7 * PW);
    int r  = f - i * (7 * PW);
    int dy = r / PW;
    int j  = r - dy * PW;
    tile4[f] = xTp4[((i * PW + h + dy) * PW + j) * 4 + bq];
  }
  __syncthreads();

  const int wt = tid & 127;                          // output w
  const int oh = tid >> 7;                           // o-pair: o = oh*2+po
  float acc[2][4] = {{0.f,0.f,0.f,0.f},{0.f,0.f,0.f,0.f}};

  for (int i = 0; i < NC; ++i) {
    const float* w0p = wsT + ((size_t)((oh * 2 + 0) * NC + i) * KK) * HWHW + h * HW + wt;
    const float* w1p = wsT + ((size_t)((oh * 2 + 1) * NC + i) * KK) * HWHW + h * HW + wt;
#pragma unroll
    for (int dy = 0; dy < 7; ++dy) {
      float4 xv[7];
      const float4* xr = &tile4[(i * 7 + dy) * PW + wt];
#pragma unroll
      for (int dx = 0; dx < 7; ++dx) xv[dx] = xr[dx];      // 7 indep ds_read_b128
#pragma unroll
      for (int dx = 0; dx < 7; ++dx) {
        const size_t toff = (size_t)(dy * 7 + dx) * HWHW;
        float wa = w0p[toff];                              // coalesced 256B/wave
        float wb = w1p[toff];
        acc[0][0] = fmaf(wa, xv[dx].x, acc[0][0]);
        acc[0][1] = fmaf(wa, xv[dx].y, acc[0][1]);
        acc[0][2] = fmaf(wa, xv[dx].z, acc[0][2]);
        acc[0][3] = fmaf(wa, xv[dx].w, acc[0][3]);
        acc[1][0] = fmaf(wb, xv[dx].x, acc[1][0]);
        acc[1][1] = fmaf(wb, xv[dx].y, acc[1][1]);
        acc[1][2] = fmaf(wb, xv[dx].z, acc[1][2]);
        acc[1][3] = fmaf(wb, xv[dx].w, acc[1][3]);
      }
    }
  }

  // mask from x tile (channel o, dy=3, wp=wt+3) + store 2o x 4b outputs
#pragma unroll
  for (int po = 0; po < 2; ++po) {
    const int o = oh * 2 + po;
    float4 m4 = tile4[(o * 7 + 3) * PW + wt + 3];
    float mx[4] = {m4.x, m4.y, m4.z, m4.w};
#pragma unroll
    for (int bb = 0; bb < 4; ++bb)
      out[(((bq * 4 + bb) * NC + o) * HW + h) * HW + wt] =
          (mx[bb] != 0.f) ? acc[po][bb] : 0.f;
  }
}

// ---------------- fallback (R3 structure) if ws too small ----------------
#define PANEL 784
#define OSTRIDE 3211264
#define ISTRIDE 802816
template <int MODE>
__global__ __launch_bounds__(256) void lc2d_main(const float* __restrict__ weight,
                                                 const float* __restrict__ xsrc,
                                                 float* __restrict__ out) {
  __shared__ __align__(16) float Raw[NC * PANEL];
  const int tid = threadIdx.x;
  const int bid = blockIdx.x;
  const int i   = bid >> 10;
  const int r2  = bid & 1023;
  const int h   = r2 >> 3;
  const int wc  = r2 & 7;
  const int w0  = wc * 16;
  const size_t wbase = (size_t)i * ISTRIDE + (size_t)(h * HW + w0) * KK;
#pragma unroll
  for (int k = 0; k < 4; ++k) {
    int f = tid + k * 256;
    if (f < 784) {
      int o = f / 196;
      int g = f - o * 196;
      *(float4*)(&Raw[o * PANEL + 4 * g]) =
          *(const float4*)(weight + wbase + (size_t)o * OSTRIDE + 4 * g);
    }
  }
  __syncthreads();
  {
    const int r    = tid >> 2;
    const int q    = tid & 3;
    const int rowb = (r >> 4) * PANEL + (r & 15) * KK;
    const int t0   = q * 12;
    float v[13];
#pragma unroll
    for (int j = 0; j < 12; ++j) v[j] = Raw[rowb + t0 + j];
    v[12] = (q == 3) ? Raw[rowb + 48] : 0.f;
    float s = 0.f;
#pragma unroll
    for (int j = 0; j < 13; ++j) s += fabsf(v[j]);
    if (q == 2) s += fabsf(v[0] + 1.f) - fabsf(v[0]);
    s += __shfl_xor(s, 1);
    s += __shfl_xor(s, 2);
    const float inv = 1.f / s;
    if (q == 2) v[0] += 1.f;
#pragma unroll
    for (int j = 0; j < 12; ++j) Raw[rowb + t0 + j] = fabsf(v[j]) * inv;
    if (q == 3) Raw[rowb + 48] = fabsf(v[12]) * inv;
  }
  __syncthreads();
  const int b   = tid & 15;
  const int pos = tid >> 4;
  const int w   = w0 + pos;
  float acc[NC] = {0.f, 0.f, 0.f, 0.f};
  float xv[7];
#pragma unroll
  for (int dy = 0; dy < 7; ++dy) {
    if (MODE == 0) {
      const float* xr = xsrc + ((size_t)((i * PW + h + dy) * PW + w) * NB + b);
#pragma unroll
      for (int dx = 0; dx < 7; ++dx) xv[dx] = xr[dx * NB];
    } else {
      int hh = h + dy - 3;
      bool hin = (hh >= 0) & (hh < HW);
#pragma unroll
      for (int dx = 0; dx < 7; ++dx) {
        int ww = w + dx - 3;
        bool in = hin & (ww >= 0) & (ww < HW);
        xv[dx] = in ? xsrc[((b * NC + i) * HW + hh) * HW + ww] : 0.f;
      }
    }
#pragma unroll
    for (int o = 0; o < NC; ++o) {
      const float* wr = &Raw[o * PANEL + pos * KK + dy * 7];
#pragma unroll
      for (int dx = 0; dx < 7; ++dx)
        acc[o] = fmaf(xv[dx], wr[dx], acc[o]);
    }
  }
#pragma unroll
  for (int o = 0; o < NC; ++o) {
    float xc;
    if (MODE == 0)
      xc = xsrc[(size_t)((o * PW + (h + 3)) * PW + (w + 3)) * NB + b];
    else
      xc = xsrc[((b * NC + o) * HW + h) * HW + w];
    atomicAdd(&out[((b * NC + o) * HW + h) * HW + w], (xc != 0.f) ? acc[o] : 0.f);
  }
}

extern "C" void kernel_launch(void* const* d_in, const int* in_sizes, int n_in,
                              void* d_out, int out_size, void* d_ws, size_t ws_size,
                              hipStream_t stream) {
  const float* x      = (const float*)d_in[0];   // (16,4,128,128) fp32
  const float* weight = (const float*)d_in[1];   // (1,4,4,128,128,49) fp32
  float* out = (float*)d_out;                    // (16,4,128,128) fp32

  const size_t xtp_bytes  = (size_t)XTP_FLOATS * 4;               // 4.6 MB
  const size_t full_bytes = (size_t)(XTP_FLOATS + WT_FLOATS) * 4; // 53.4 MiB

  if (ws_size >= full_bytes) {
    float* xTp = (float*)d_ws;
    float* wsT = (float*)d_ws + XTP_FLOATS;
    lc2d_prep <<<(NC * PW * PW + 255) / 256, 256, 0, stream>>>(x, xTp);
    lc2d_wnorm<<<4096, 256, 0, stream>>>(weight, wsT);
    lc2d_fused2<<<512, 256, 0, stream>>>(wsT, xTp, out);
  } else if (ws_size >= xtp_bytes) {
    hipMemsetAsync(d_out, 0, (size_t)out_size * sizeof(float), stream);
    float* xTp = (float*)d_ws;
    lc2d_prep<<<(NC * PW * PW + 255) / 256, 256, 0, stream>>>(x, xTp);
    lc2d_main<0><<<4096, 256, 0, stream>>>(weight, xTp, out);
  } else {
    hipMemsetAsync(d_out, 0, (size_t)out_size * sizeof(float), stream);
    lc2d_main<1><<<4096, 256, 0, stream>>>(weight, x, out);
  }
}